// Round 1
// baseline (65.282 us; speedup 1.0000x reference)
//
#include <hip/hip_runtime.h>

#define HH   48
#define WW   96
#define CC   256
#define RRAD 4
#define DD   9
#define DD2  81
#define PP   10
#define HWSZ (HH * WW)

// ---------------- kernel 1: (C,H,W) -> (H,W,C) transpose ----------------
// tile: 64 channels x 64 pixels; blockIdx.y selects f1 vs f2
__global__ __launch_bounds__(256) void transpose_chw_hwc(
    const float* __restrict__ f1, const float* __restrict__ f2,
    float* __restrict__ f1t, float* __restrict__ f2t) {
  __shared__ float tile[64][65];
  const float* src = (blockIdx.y == 0) ? f1 : f2;
  float* dst = (blockIdx.y == 0) ? f1t : f2t;

  const int tid = threadIdx.x;
  const int tiles_p = HWSZ / 64;            // 72
  const int bc = blockIdx.x / tiles_p;      // 0..3  (channel tile)
  const int bp = blockIdx.x % tiles_p;      // 0..71 (pixel tile)
  const int c0 = bc * 64, p0 = bp * 64;

#pragma unroll
  for (int k = 0; k < 16; k++) {
    int idx = k * 256 + tid;
    int cl = idx >> 6, pl = idx & 63;       // consecutive tid -> consecutive pixel: coalesced read
    tile[cl][pl] = src[(size_t)(c0 + cl) * HWSZ + p0 + pl];
  }
  __syncthreads();
#pragma unroll
  for (int k = 0; k < 16; k++) {
    int idx = k * 256 + tid;
    int pl = idx >> 6, cl = idx & 63;       // consecutive tid -> consecutive channel: coalesced write
    dst[(size_t)(p0 + pl) * CC + c0 + cl] = tile[cl][pl];
  }
}

// ---------------- kernel 2: correlation + DAP, one block per pixel ----------------
__global__ __launch_bounds__(256) void corr_main(
    const float* __restrict__ f1t, const float* __restrict__ f2t,
    const float* __restrict__ coords, const float* __restrict__ w_dap,
    float* __restrict__ out) {
  __shared__ float f1s[CC];
  __shared__ float dots[PP * PP];
  __shared__ float corrs[DD2];
  __shared__ float partial[3][DD2];

  const int p = blockIdx.x;                 // pixel index h*W+w
  const int tid = threadIdx.x;

  const float cx = coords[p];
  const float cy = coords[HWSZ + p];
  const float fxf = floorf(cx), fyf = floorf(cy);
  const float fx = cx - fxf, fy = cy - fyf; // fractional weights, shared by all 81 offsets
  const int xb = (int)fxf - RRAD;           // patch origin
  const int yb = (int)fyf - RRAD;

  f1s[tid] = f1t[(size_t)p * CC + tid];
  __syncthreads();

  const int wid = tid >> 6, lane = tid & 63;
  const float4 a = *reinterpret_cast<const float4*>(&f1s[lane * 4]);

  // 100 dot products: wave 'wid' handles dd = wid, wid+4, ...
  for (int dd = wid; dd < PP * PP; dd += 4) {
    const int yy = dd / PP, xx = dd - yy * PP;
    const int gy = yb + yy, gx = xb + xx;
    float v = 0.f;
    if (gx >= 0 && gx < WW && gy >= 0 && gy < HH) {
      const float4 b = *reinterpret_cast<const float4*>(
          &f2t[(size_t)(gy * WW + gx) * CC + lane * 4]);
      v = a.x * b.x + a.y * b.y + a.z * b.z + a.w * b.w;
    }
#pragma unroll
    for (int off = 32; off; off >>= 1) v += __shfl_down(v, off, 64);
    if (lane == 0) dots[dd] = v;
  }
  __syncthreads();

  // 81 bilinear combines; d = i*9 + j, i = x-offset idx, j = y-offset idx
  if (tid < DD2) {
    const int i = tid / DD, j = tid - i * DD;
    const float d00 = dots[j * PP + i];
    const float d01 = dots[j * PP + i + 1];
    const float d10 = dots[(j + 1) * PP + i];
    const float d11 = dots[(j + 1) * PP + i + 1];
    const float c = (1.f - fy) * ((1.f - fx) * d00 + fx * d01) +
                    fy * ((1.f - fx) * d10 + fx * d11);
    corrs[tid] = c * 0.0625f;               // 1/sqrt(256)
  }
  __syncthreads();

  // DAP: out[o] = sum_d w_dap[o,d] * corrs[d]; 243 threads, 27 d's each
  if (tid < 243) {
    const int o = tid % DD2, chunk = tid / DD2;
    const int d0 = chunk * 27;
    float acc = 0.f;
#pragma unroll
    for (int d = 0; d < 27; d++) acc += w_dap[o * DD2 + d0 + d] * corrs[d0 + d];
    partial[chunk][o] = acc;
  }
  __syncthreads();
  if (tid < DD2) {
    out[(size_t)tid * HWSZ + p] = partial[0][tid] + partial[1][tid] + partial[2][tid];
  }
}

extern "C" void kernel_launch(void* const* d_in, const int* in_sizes, int n_in,
                              void* d_out, int out_size, void* d_ws, size_t ws_size,
                              hipStream_t stream) {
  const float* f1     = (const float*)d_in[0];
  const float* f2     = (const float*)d_in[1];
  const float* coords = (const float*)d_in[2];
  const float* w_dap  = (const float*)d_in[3];
  float* out = (float*)d_out;

  float* f1t = (float*)d_ws;                          // HWSZ*CC floats
  float* f2t = f1t + (size_t)HWSZ * CC;               // HWSZ*CC floats

  dim3 tgrid((CC / 64) * (HWSZ / 64), 2);
  transpose_chw_hwc<<<tgrid, 256, 0, stream>>>(f1, f2, f1t, f2t);

  corr_main<<<dim3(HWSZ), 256, 0, stream>>>(f1t, f2t, coords, w_dap, out);
}

// Round 2
// 44.731 us; speedup vs baseline: 1.4594x; 1.4594x over previous
//
#include <hip/hip_runtime.h>

#define HH   48
#define WW   96
#define CC   256
#define RRAD 4
#define DD   9
#define DD2  81
#define PP   10
#define HWSZ (HH * WW)

// ---------------- kernel 1: (C,H,W) -> (H,W,C) transpose ----------------
__global__ __launch_bounds__(256) void transpose_chw_hwc(
    const float* __restrict__ f1, const float* __restrict__ f2,
    float* __restrict__ f1t, float* __restrict__ f2t) {
  __shared__ float tile[64][65];
  const float* src = (blockIdx.y == 0) ? f1 : f2;
  float* dst = (blockIdx.y == 0) ? f1t : f2t;

  const int tid = threadIdx.x;
  const int tiles_p = HWSZ / 64;            // 72
  const int bc = blockIdx.x / tiles_p;      // 0..3  (channel tile)
  const int bp = blockIdx.x % tiles_p;      // 0..71 (pixel tile)
  const int c0 = bc * 64, p0 = bp * 64;

#pragma unroll
  for (int k = 0; k < 16; k++) {
    int idx = k * 256 + tid;
    int cl = idx >> 6, pl = idx & 63;
    tile[cl][pl] = src[(size_t)(c0 + cl) * HWSZ + p0 + pl];
  }
  __syncthreads();
#pragma unroll
  for (int k = 0; k < 16; k++) {
    int idx = k * 256 + tid;
    int pl = idx >> 6, cl = idx & 63;
    dst[(size_t)(p0 + pl) * CC + c0 + cl] = tile[cl][pl];
  }
}

// 16-lane sum reduce, 4 full-rate DPP adds (no ds_bpermute).
// quad_perm(1,0,3,2)=0xB1, quad_perm(2,3,0,1)=0x4E,
// ROW_HALF_MIRROR=0x141, ROW_MIRROR=0x140 — all stay within a row of 16.
__device__ __forceinline__ float red16(float v) {
  int x;
  x = __builtin_amdgcn_update_dpp(0, __float_as_int(v), 0xB1, 0xF, 0xF, true);
  v += __int_as_float(x);
  x = __builtin_amdgcn_update_dpp(0, __float_as_int(v), 0x4E, 0xF, 0xF, true);
  v += __int_as_float(x);
  x = __builtin_amdgcn_update_dpp(0, __float_as_int(v), 0x141, 0xF, 0xF, true);
  v += __int_as_float(x);
  x = __builtin_amdgcn_update_dpp(0, __float_as_int(v), 0x140, 0xF, 0xF, true);
  v += __int_as_float(x);
  return v;
}

// ---------------- kernel 2: correlation + DAP, one block per pixel ----------------
__global__ __launch_bounds__(256) void corr_main(
    const float* __restrict__ f1t, const float* __restrict__ f2t,
    const float* __restrict__ coords, const float* __restrict__ w_dap,
    float* __restrict__ out) {
  __shared__ float f1s[CC];
  __shared__ float dots[PP * PP];
  __shared__ float corrs[DD2];
  __shared__ float partial[3][DD2];

  const int p = blockIdx.x;                 // pixel index h*W+w
  const int tid = threadIdx.x;

  const float cx = coords[p];
  const float cy = coords[HWSZ + p];
  const float fxf = floorf(cx), fyf = floorf(cy);
  const float fx = cx - fxf, fy = cy - fyf; // fractional weights shared by all 81 offsets
  const int xb = (int)fxf - RRAD;           // patch origin
  const int yb = (int)fyf - RRAD;

  f1s[tid] = f1t[(size_t)p * CC + tid];
  __syncthreads();

  const int wid = tid >> 6, lane = tid & 63;
  const int di = lane >> 4;                 // which of 4 concurrent dots in this wave
  const int q  = lane & 15;                 // channel-slice owner (16 ch each)

  // f1 fragment: channels q*4 + k*64 .. +3  (4 x float4 = 16 channels)
  float4 a[4];
#pragma unroll
  for (int k = 0; k < 4; k++) a[k] = *reinterpret_cast<const float4*>(&f1s[q * 4 + k * 64]);

  // 100 dots; per pass each wave computes 4 dots with 16 lanes each
  for (int dd0 = wid * 4; dd0 < PP * PP; dd0 += 16) {
    const int dd = dd0 + di;
    const int yy = dd / PP, xx = dd - yy * PP;
    const int gy = yb + yy, gx = xb + xx;
    float acc = 0.f;
    if (gx >= 0 && gx < WW && gy >= 0 && gy < HH) {
      const float* bp = &f2t[(size_t)(gy * WW + gx) * CC];
#pragma unroll
      for (int k = 0; k < 4; k++) {
        const float4 b = *reinterpret_cast<const float4*>(&bp[q * 4 + k * 64]);
        acc += a[k].x * b.x + a[k].y * b.y + a[k].z * b.z + a[k].w * b.w;
      }
    }
    const float v = red16(acc);
    if (q == 0) dots[dd] = v;
  }
  __syncthreads();

  // 81 bilinear combines; d = i*9 + j, i = x-offset idx, j = y-offset idx
  if (tid < DD2) {
    const int i = tid / DD, j = tid - i * DD;
    const float d00 = dots[j * PP + i];
    const float d01 = dots[j * PP + i + 1];
    const float d10 = dots[(j + 1) * PP + i];
    const float d11 = dots[(j + 1) * PP + i + 1];
    const float c = (1.f - fy) * ((1.f - fx) * d00 + fx * d01) +
                    fy * ((1.f - fx) * d10 + fx * d11);
    corrs[tid] = c * 0.0625f;               // 1/sqrt(256)
  }
  __syncthreads();

  // DAP: out[o] = sum_d w_dap[o,d] * corrs[d]; 243 threads, 27 d's each
  if (tid < 243) {
    const int o = tid % DD2, chunk = tid / DD2;
    const int d0 = chunk * 27;
    float acc = 0.f;
#pragma unroll
    for (int d = 0; d < 27; d++) acc += w_dap[o * DD2 + d0 + d] * corrs[d0 + d];
    partial[chunk][o] = acc;
  }
  __syncthreads();
  if (tid < DD2) {
    out[(size_t)tid * HWSZ + p] = partial[0][tid] + partial[1][tid] + partial[2][tid];
  }
}

extern "C" void kernel_launch(void* const* d_in, const int* in_sizes, int n_in,
                              void* d_out, int out_size, void* d_ws, size_t ws_size,
                              hipStream_t stream) {
  const float* f1     = (const float*)d_in[0];
  const float* f2     = (const float*)d_in[1];
  const float* coords = (const float*)d_in[2];
  const float* w_dap  = (const float*)d_in[3];
  float* out = (float*)d_out;

  float* f1t = (float*)d_ws;                          // HWSZ*CC floats
  float* f2t = f1t + (size_t)HWSZ * CC;               // HWSZ*CC floats

  dim3 tgrid((CC / 64) * (HWSZ / 64), 2);
  transpose_chw_hwc<<<tgrid, 256, 0, stream>>>(f1, f2, f1t, f2t);

  corr_main<<<dim3(HWSZ), 256, 0, stream>>>(f1t, f2t, coords, w_dap, out);
}